// Round 3
// baseline (299741.016 us; speedup 1.0000x reference)
//
#include <hip/hip_runtime.h>
#include <hip/hip_bf16.h>

#define S_ 512
#define B_ 128
#define D_ 128
#define H_ 512
#define NB_ 240

typedef short bf16x8 __attribute__((ext_vector_type(8)));
typedef float f32x4 __attribute__((ext_vector_type(4)));

// ---- weight plane offsets (in shorts). 3 planes, plane stride WPLANE. ----
#define OFF0_XI   0
#define OFF0_HI   131072
#define OFF0_OX   655360
#define OFF0_OH   720896
#define OFF0_IO   983040
#define OFF0_HO   1245184
#define OFF0_CHO  1507328
#define OFF0_A    1769472
#define OFF0_B    2031616
#define OFF1_XI   2293760
#define OFF1_HI   2818048
#define OFF1_OX   3342336
#define OFF1_OH   3604480
#define OFF1_IO   3866624
#define OFF1_HO   4128768
#define OFF1_CHO  4390912
#define OFF1_A    4653056
#define OFF1_B    4915200
#define WPLANE    5177344
#define APLANE    65536

__device__ __forceinline__ float sigf(float x) { return 1.0f / (1.0f + expf(-x)); }

__device__ __forceinline__ short bfs(float v) {
  __hip_bfloat16 h = __float2bfloat16(v);
  return __builtin_bit_cast(short, h);
}
__device__ __forceinline__ float bff(short s) {
  __hip_bfloat16 h = __builtin_bit_cast(__hip_bfloat16, s);
  return __bfloat162float(h);
}

__device__ __forceinline__ void st3(short* buf, int idx, float v) {
  short s0 = bfs(v);
  float f0 = bff(s0);
  float r1 = v - f0;
  short s1 = bfs(r1);
  float f1 = bff(s1);
  short s2 = bfs(r1 - f1);
  buf[idx] = s0;
  buf[idx + APLANE] = s1;
  buf[idx + 2 * APLANE] = s2;
}
__device__ __forceinline__ float ld3(const short* buf, int idx) {
  return bff(buf[idx]) + bff(buf[idx + APLANE]) + bff(buf[idx + 2 * APLANE]);
}

#define MFMA16(a, b, c) __builtin_amdgcn_mfma_f32_16x16x32_bf16(a, b, c, 0, 0, 0)

struct AFrag {
  bf16x8 a0, a1, a2;
};

__device__ __forceinline__ AFrag ldA(const short* base) {
  AFrag f;
  f.a0 = *(const bf16x8*)(base);
  f.a1 = *(const bf16x8*)(base + APLANE);
  f.a2 = *(const bf16x8*)(base + 2 * APLANE);
  return f;
}

// on-the-fly 3-plane split of fp32 input x
__device__ __forceinline__ AFrag ldAx(const float* base) {
  AFrag f;
#pragma unroll
  for (int e = 0; e < 8; ++e) {
    float xv = base[e];
    short s0 = bfs(xv);
    float f0 = bff(s0);
    float r1 = xv - f0;
    short s1 = bfs(r1);
    float f1 = bff(s1);
    short s2 = bfs(r1 - f1);
    f.a0[e] = s0;
    f.a1[e] = s1;
    f.a2[e] = s2;
  }
  return f;
}

__device__ __forceinline__ void mac6(f32x4& acc, const AFrag& A, const bf16x8& W0,
                                     const bf16x8& W1, const bf16x8& W2) {
  acc = MFMA16(A.a0, W0, acc);
  acc = MFMA16(A.a0, W1, acc);
  acc = MFMA16(A.a1, W0, acc);
  acc = MFMA16(A.a0, W2, acc);
  acc = MFMA16(A.a1, W1, acc);
  acc = MFMA16(A.a2, W0, acc);
}

// LDS weight slab read, XOR-swizzled (kills the stride-1KB 16-way bank conflict).
__device__ __forceinline__ bf16x8 ldW(int slab, int K2, int r, int kb) {
  extern __shared__ char smem[];
  return *(const bf16x8*)(smem + slab + ((r * K2 + kb) ^ ((r & 7) << 4)));
}

// stage one 16-row x K plane slab global->LDS with the same swizzle (once, at start)
__device__ __forceinline__ void stage(int slabBase, const short* src, int K) {
  extern __shared__ char smem[];
  const int kc8 = K / 8;
  const int chunks = 16 * kc8;
  for (int c = threadIdx.x; c < chunks; c += blockDim.x) {
    const int row = c / kc8, kc = c % kc8;
    bf16x8 v = *(const bf16x8*)(src + row * K + kc * 8);
    *(bf16x8*)(smem + slabBase + ((row * (2 * K) + kc * 16) ^ ((row & 7) << 4))) = v;
  }
}

// ---- device-scope grid barrier (all NB_ blocks co-resident by capacity) ----
__device__ __forceinline__ void gbar(int* cnt, int* gen) {
  __syncthreads();  // drains each wave's stores (vmcnt 0 before s_barrier)
  if (threadIdx.x == 0) {
    const int g0 = __hip_atomic_load(gen, __ATOMIC_RELAXED, __HIP_MEMORY_SCOPE_AGENT);
    __threadfence();  // release: flush this XCD's dirty L2 to coherence point
    if (__hip_atomic_fetch_add(cnt, 1, __ATOMIC_ACQ_REL, __HIP_MEMORY_SCOPE_AGENT) ==
        NB_ - 1) {
      __hip_atomic_store(cnt, 0, __ATOMIC_RELAXED, __HIP_MEMORY_SCOPE_AGENT);
      __hip_atomic_fetch_add(gen, 1, __ATOMIC_RELEASE, __HIP_MEMORY_SCOPE_AGENT);
    } else {
      while (__hip_atomic_load(gen, __ATOMIC_ACQUIRE, __HIP_MEMORY_SCOPE_AGENT) == g0)
        __builtin_amdgcn_s_sleep(2);
    }
    __threadfence();  // acquire: invalidate stale L1/L2 before next phase reads
  }
  __syncthreads();
}

struct PArgs {
  const float* x;
  const short* Wb;
  short* h0s;
  short* h1s;
  short* xn0;
  short* hn0;
  short* ch0;
  short* xn1;
  short* hn1;
  short* ch1;
  short* o0;
  short* o1;
  const float* bhi0;
  const float* bcho0;
  const float* bhi1;
  const float* bcho1;
  float* out;
  int* cnt;
  int* gen;
};

// Block map: 0-31 L1-gate | 32-63 L0-gate | 64-79 L0 xn/hn | 80-111 L1 xn/hn
//            112-143 B-L0 | 144-175 B-L1 | 176-207 C-L0 | 208-239 C-L1
__global__ __launch_bounds__(512, 2) void eltm_persist(PArgs p) {
  const int bid = blockIdx.x;
  const int lane = threadIdx.x & 63;
  const int w = threadIdx.x >> 6;
  const int r = lane & 15;
  const int g = lane >> 4;
  const f32x4 z = {0.f, 0.f, 0.f, 0.f};

  // ---------------- one-time LDS weight staging ----------------
  if (bid < 32) {  // L1-gate: [xiIg p0,p1][hiIg p0,p1][xiHg p0,p1][hiHg p0,p1] @16KB
    const int j0 = bid * 16;
    stage(0, p.Wb + OFF1_XI + j0 * 512, 512);
    stage(16384, p.Wb + OFF1_XI + WPLANE + j0 * 512, 512);
    stage(32768, p.Wb + OFF1_HI + j0 * 512, 512);
    stage(49152, p.Wb + OFF1_HI + WPLANE + j0 * 512, 512);
    stage(65536, p.Wb + OFF1_XI + (512 + j0) * 512, 512);
    stage(81920, p.Wb + OFF1_XI + WPLANE + (512 + j0) * 512, 512);
    stage(98304, p.Wb + OFF1_HI + (512 + j0) * 512, 512);
    stage(114688, p.Wb + OFF1_HI + WPLANE + (512 + j0) * 512, 512);
  } else if (bid < 64) {  // L0-gate: xiIg/xiHg 3x4KB, hiIg/hiHg 3x16KB
    const int j0 = (bid - 32) * 16;
    for (int pl = 0; pl < 3; ++pl) {
      stage(pl * 4096, p.Wb + OFF0_XI + pl * WPLANE + j0 * 128, 128);
      stage(12288 + pl * 4096, p.Wb + OFF0_XI + pl * WPLANE + (512 + j0) * 128, 128);
      stage(24576 + pl * 16384, p.Wb + OFF0_HI + pl * WPLANE + j0 * 512, 512);
      stage(73728 + pl * 16384, p.Wb + OFF0_HI + pl * WPLANE + (512 + j0) * 512, 512);
    }
  } else if (bid < 80) {  // L0 xn/hn: 2 col-tiles x (ox 3x4KB + oh 3x16KB)
    const int j0 = (bid - 64) * 32;
    for (int c = 0; c < 2; ++c) {
      const int base = c * 61440;
      for (int pl = 0; pl < 3; ++pl) {
        stage(base + pl * 4096, p.Wb + OFF0_OX + pl * WPLANE + (j0 + c * 16) * 128, 128);
        stage(base + 12288 + pl * 16384,
              p.Wb + OFF0_OH + pl * WPLANE + (j0 + c * 16) * 512, 512);
      }
    }
  } else if (bid < 112) {  // L1 xn/hn: ox1 3x16KB, oh1 3x16KB
    const int j0 = (bid - 80) * 16;
    for (int pl = 0; pl < 3; ++pl) {
      stage(pl * 16384, p.Wb + OFF1_OX + pl * WPLANE + j0 * 512, 512);
      stage(49152 + pl * 16384, p.Wb + OFF1_OH + pl * WPLANE + j0 * 512, 512);
    }
  } else if (bid < 176) {  // B: io/ho/cho 3x16KB each = 144KB
    const int L = bid >= 144;
    const int j0 = (bid - (L ? 144 : 112)) * 16;
    const int oio = L ? OFF1_IO : OFF0_IO;
    const int oho = L ? OFF1_HO : OFF0_HO;
    const int och = L ? OFF1_CHO : OFF0_CHO;
    for (int pl = 0; pl < 3; ++pl) {
      stage(pl * 16384, p.Wb + oio + pl * WPLANE + j0 * 512, 512);
      stage(49152 + pl * 16384, p.Wb + oho + pl * WPLANE + j0 * 512, 512);
      stage(98304 + pl * 16384, p.Wb + och + pl * WPLANE + j0 * 512, 512);
    }
  } else {  // C: wa/wb 3x16KB each = 96KB
    const int L = bid >= 208;
    const int j0 = (bid - (L ? 208 : 176)) * 16;
    const int oa = L ? OFF1_A : OFF0_A;
    const int ob = L ? OFF1_B : OFF0_B;
    for (int pl = 0; pl < 3; ++pl) {
      stage(pl * 16384, p.Wb + oa + pl * WPLANE + j0 * 512, 512);
      stage(49152 + pl * 16384, p.Wb + ob + pl * WPLANE + j0 * 512, 512);
    }
  }
  __syncthreads();

  // ---------------- recurrence ----------------
  for (int i = 0; i <= S_; ++i) {
    const int do0 = i < S_;
    const int do1 = i >= 1;
    // ============ phase A ============
    if (bid < 32) {
      if (do1) {  // L1 gates -> ch1 (step i-1). W2 plane streamed from global.
        const int j0 = bid * 16;
        const int m0 = w * 16;
        f32x4 ig = z, hg = z;
        const short* a0 = p.h0s + (m0 + r) * H_ + g * 8;
        const short* w2xi = p.Wb + OFF1_XI + 2 * WPLANE + (j0 + r) * 512 + g * 8;
        const short* w2xh = p.Wb + OFF1_XI + 2 * WPLANE + (512 + j0 + r) * 512 + g * 8;
        for (int ks = 0; ks < 16; ++ks) {
          AFrag A = ldA(a0 + ks * 32);
          const int kb = ks * 64 + g * 16;
          mac6(ig, A, ldW(0, 1024, r, kb), ldW(16384, 1024, r, kb),
               *(const bf16x8*)(w2xi + ks * 32));
          mac6(hg, A, ldW(65536, 1024, r, kb), ldW(81920, 1024, r, kb),
               *(const bf16x8*)(w2xh + ks * 32));
        }
        const short* a1 = p.h1s + (m0 + r) * H_ + g * 8;
        const short* w2hi = p.Wb + OFF1_HI + 2 * WPLANE + (j0 + r) * 512 + g * 8;
        const short* w2hh = p.Wb + OFF1_HI + 2 * WPLANE + (512 + j0 + r) * 512 + g * 8;
        for (int ks = 0; ks < 16; ++ks) {
          AFrag A = ldA(a1 + ks * 32);
          const int kb = ks * 64 + g * 16;
          mac6(ig, A, ldW(32768, 1024, r, kb), ldW(49152, 1024, r, kb),
               *(const bf16x8*)(w2hi + ks * 32));
          mac6(hg, A, ldW(98304, 1024, r, kb), ldW(114688, 1024, r, kb),
               *(const bf16x8*)(w2hh + ks * 32));
        }
        const int n = j0 + r;
        const float bi = p.bhi1[n], bh = p.bhi1[512 + n];
#pragma unroll
        for (int e = 0; e < 4; ++e)
          st3(p.ch1, (m0 + g * 4 + e) * H_ + n, sigf(ig[e] + bi) * tanhf(hg[e] + bh));
      }
    } else if (bid < 64) {
      if (do0) {  // L0 gates -> ch0 (step i)
        const int j0 = (bid - 32) * 16;
        const int m0 = w * 16;
        f32x4 ig = z, hg = z;
        const float* xr = p.x + (size_t)i * B_ * D_ + (m0 + r) * D_ + g * 8;
        for (int ks = 0; ks < 4; ++ks) {
          AFrag A = ldAx(xr + ks * 32);
          const int kb = ks * 64 + g * 16;
          mac6(ig, A, ldW(0, 256, r, kb), ldW(4096, 256, r, kb), ldW(8192, 256, r, kb));
          mac6(hg, A, ldW(12288, 256, r, kb), ldW(16384, 256, r, kb),
               ldW(20480, 256, r, kb));
        }
        const short* a0 = p.h0s + (m0 + r) * H_ + g * 8;
        for (int ks = 0; ks < 16; ++ks) {
          AFrag A = ldA(a0 + ks * 32);
          const int kb = ks * 64 + g * 16;
          mac6(ig, A, ldW(24576, 1024, r, kb), ldW(40960, 1024, r, kb),
               ldW(57344, 1024, r, kb));
          mac6(hg, A, ldW(73728, 1024, r, kb), ldW(90112, 1024, r, kb),
               ldW(106496, 1024, r, kb));
        }
        const int n = j0 + r;
        const float bi = p.bhi0[n], bh = p.bhi0[512 + n];
#pragma unroll
        for (int e = 0; e < 4; ++e)
          st3(p.ch0, (m0 + g * 4 + e) * H_ + n, sigf(ig[e] + bi) * tanhf(hg[e] + bh));
      }
    } else if (bid < 80) {
      if (do0) {  // L0 xn,hn (step i): 4 units/wave (2 xn + 2 hn)
        const int j0 = (bid - 64) * 32;
        const int m0 = w * 16;
        for (int u = 0; u < 4; ++u) {
          const int col = u & 1;
          const int gm = u >> 1;
          const int base = col * 61440;
          f32x4 acc = z;
          if (gm == 0) {
            const float* xr = p.x + (size_t)i * B_ * D_ + (m0 + r) * D_ + g * 8;
            for (int ks = 0; ks < 4; ++ks) {
              AFrag A = ldAx(xr + ks * 32);
              const int kb = ks * 64 + g * 16;
              mac6(acc, A, ldW(base, 256, r, kb), ldW(base + 4096, 256, r, kb),
                   ldW(base + 8192, 256, r, kb));
            }
          } else {
            const short* a0 = p.h0s + (m0 + r) * H_ + g * 8;
            for (int ks = 0; ks < 16; ++ks) {
              AFrag A = ldA(a0 + ks * 32);
              const int kb = ks * 64 + g * 16;
              mac6(acc, A, ldW(base + 12288, 1024, r, kb),
                   ldW(base + 28672, 1024, r, kb), ldW(base + 45056, 1024, r, kb));
            }
          }
          const int n = j0 + col * 16 + r;
          short* dst = gm ? p.hn0 : p.xn0;
#pragma unroll
          for (int e = 0; e < 4; ++e)
            st3(dst, (m0 + g * 4 + e) * H_ + n, tanhf(acc[e]));
        }
      }
    } else if (bid < 112) {
      if (do1) {  // L1 xn,hn (step i-1)
        const int j0 = (bid - 80) * 16;
        const int m0 = w * 16;
        for (int gm = 0; gm < 2; ++gm) {
          f32x4 acc = z;
          const short* a = (gm ? p.h1s : p.h0s) + (m0 + r) * H_ + g * 8;
          const int sb = gm * 49152;
          for (int ks = 0; ks < 16; ++ks) {
            AFrag A = ldA(a + ks * 32);
            const int kb = ks * 64 + g * 16;
            mac6(acc, A, ldW(sb, 1024, r, kb), ldW(sb + 16384, 1024, r, kb),
                 ldW(sb + 32768, 1024, r, kb));
          }
          const int n = j0 + r;
          short* dst = gm ? p.hn1 : p.xn1;
#pragma unroll
          for (int e = 0; e < 4; ++e)
            st3(dst, (m0 + g * 4 + e) * H_ + n, tanhf(acc[e]));
        }
      }
    }
    gbar(p.cnt, p.gen);

    // ============ phase B ============
    if (bid >= 112 && bid < 176) {
      const int L = bid >= 144;
      if (L ? do1 : do0) {
        const int j0 = (bid - (L ? 144 : 112)) * 16;
        const int m0 = w * 16;
        const short* xn = L ? p.xn1 : p.xn0;
        const short* hn = L ? p.hn1 : p.hn0;
        const short* ch = L ? p.ch1 : p.ch0;
        f32x4 aA = z, aB = z;
        const short* ax = xn + (m0 + r) * H_ + g * 8;
        for (int ks = 0; ks < 16; ++ks) {
          AFrag A = ldA(ax + ks * 32);
          const int kb = ks * 64 + g * 16;
          mac6(aA, A, ldW(0, 1024, r, kb), ldW(16384, 1024, r, kb),
               ldW(32768, 1024, r, kb));
        }
        const short* ah = hn + (m0 + r) * H_ + g * 8;
        for (int ks = 0; ks < 16; ++ks) {
          AFrag A = ldA(ah + ks * 32);
          const int kb = ks * 64 + g * 16;
          mac6(aB, A, ldW(49152, 1024, r, kb), ldW(65536, 1024, r, kb),
               ldW(81920, 1024, r, kb));
        }
        const short* ac = ch + (m0 + r) * H_ + g * 8;
        for (int ks = 0; ks < 16; ++ks) {
          AFrag A = ldA(ac + ks * 32);
          const int kb = ks * 64 + g * 16;
          if (ks & 1)
            mac6(aB, A, ldW(98304, 1024, r, kb), ldW(114688, 1024, r, kb),
                 ldW(131072, 1024, r, kb));
          else
            mac6(aA, A, ldW(98304, 1024, r, kb), ldW(114688, 1024, r, kb),
                 ldW(131072, 1024, r, kb));
        }
        const int n = j0 + r;
        const float bc = (L ? p.bcho1 : p.bcho0)[n];
        short* o = L ? p.o1 : p.o0;
#pragma unroll
        for (int e = 0; e < 4; ++e)
          st3(o, (m0 + g * 4 + e) * H_ + n, sigf(aA[e] + aB[e] + bc));
      }
    }
    gbar(p.cnt, p.gen);

    // ============ phase C ============
    if (bid >= 176) {
      const int L = bid >= 208;
      if (L ? do1 : do0) {
        const int j0 = (bid - (L ? 208 : 176)) * 16;
        const int m0 = w * 16;
        const short* o = L ? p.o1 : p.o0;
        f32x4 aA = z, aB = z;
        const short* ao = o + (m0 + r) * H_ + g * 8;
        for (int ks = 0; ks < 16; ++ks) {
          AFrag A = ldA(ao + ks * 32);
          const int kb = ks * 64 + g * 16;
          mac6(aA, A, ldW(0, 1024, r, kb), ldW(16384, 1024, r, kb),
               ldW(32768, 1024, r, kb));
          mac6(aB, A, ldW(49152, 1024, r, kb), ldW(65536, 1024, r, kb),
               ldW(81920, 1024, r, kb));
        }
        const int n = j0 + r;
        const short* xn = L ? p.xn1 : p.xn0;
        const short* hn = L ? p.hn1 : p.hn0;
        const short* ch = L ? p.ch1 : p.ch0;
        short* hs = L ? p.h1s : p.h0s;
#pragma unroll
        for (int e = 0; e < 4; ++e) {
          const int idx = (m0 + g * 4 + e) * H_ + n;
          const float av = aA[e], bv = aB[e];
          const float hv =
              av * ld3(xn, idx) + bv * ld3(hn, idx) + (1.f - av - bv) * ld3(ch, idx);
          st3(hs, idx, hv);
          if (L) p.out[(size_t)(i - 1) * B_ * H_ + idx] = hv;
        }
      }
    }
    gbar(p.cnt, p.gen);
  }
}

// ---------------- prologue: split fp32 weights into 3 bf16 planes ----------------
__global__ void wsplit(const float* __restrict__ src, short* __restrict__ dst, int n) {
  int i = blockIdx.x * 256 + threadIdx.x;
  if (i >= n) return;
  float v = src[i];
  short s0 = bfs(v);
  float f0 = bff(s0);
  float r1 = v - f0;
  short s1 = bfs(r1);
  float f1 = bff(s1);
  short s2 = bfs(r1 - f1);
  dst[i] = s0;
  dst[i + WPLANE] = s1;
  dst[i + 2 * WPLANE] = s2;
}

// ---------------- final: in-place sinrelu + LayerNorm over H on d_out ----------------
__global__ void eltm_kLN(float* __restrict__ out, const float* __restrict__ g,
                         const float* __restrict__ bta) {
  const int row = blockIdx.x * 4 + (threadIdx.x >> 6);
  const int lane = threadIdx.x & 63;
  float* r = out + (size_t)row * H_;
  float v[8];
  float s = 0.f, s2 = 0.f;
#pragma unroll
  for (int i = 0; i < 8; ++i) {
    float x = r[lane + i * 64];
    float sv = (x >= 0.f) ? (x + sinf(x)) : 0.f;
    v[i] = sv;
    s += sv;
    s2 += sv * sv;
  }
#pragma unroll
  for (int m = 1; m < 64; m <<= 1) {
    s += __shfl_xor(s, m);
    s2 += __shfl_xor(s2, m);
  }
  const float mean = s * (1.f / 512.f);
  const float var = s2 * (1.f / 512.f) - mean * mean;
  const float rstd = rsqrtf(var + 1e-5f);
#pragma unroll
  for (int i = 0; i < 8; ++i) {
    const int c = lane + i * 64;
    r[c] = (v[i] - mean) * rstd * g[c] + bta[c];
  }
}

extern "C" void kernel_launch(void* const* d_in, const int* in_sizes, int n_in,
                              void* d_out, int out_size, void* d_ws, size_t ws_size,
                              hipStream_t stream) {
  const float* x = (const float*)d_in[0];
#define W(i) ((const float*)d_in[i])
  short* Wb = (short*)d_ws;
  short* acts = (short*)((char*)d_ws + (size_t)3 * WPLANE * 2);
  const int ASZ = 3 * APLANE;
  short* h0s = acts;
  short* h1s = acts + ASZ;
  short* xn0 = acts + 2 * ASZ;
  short* hn0 = acts + 3 * ASZ;
  short* ch0 = acts + 4 * ASZ;
  short* xn1 = acts + 5 * ASZ;
  short* hn1 = acts + 6 * ASZ;
  short* ch1 = acts + 7 * ASZ;
  short* o0 = acts + 8 * ASZ;
  short* o1 = acts + 9 * ASZ;
  int* bar = (int*)(acts + 10 * ASZ);
  float* out = (float*)d_out;

  struct {
    int src;
    int off;
    int n;
  } wl[18] = {{1, OFF0_XI, 131072},   {2, OFF0_HI, 524288},  {4, OFF0_OX, 65536},
              {5, OFF0_OH, 262144},   {6, OFF0_IO, 262144},  {7, OFF0_HO, 262144},
              {8, OFF0_CHO, 262144},  {10, OFF0_A, 262144},  {11, OFF0_B, 262144},
              {12, OFF1_XI, 524288},  {13, OFF1_HI, 524288}, {15, OFF1_OX, 262144},
              {16, OFF1_OH, 262144},  {17, OFF1_IO, 262144}, {18, OFF1_HO, 262144},
              {19, OFF1_CHO, 262144}, {21, OFF1_A, 262144},  {22, OFF1_B, 262144}};
  for (int i = 0; i < 18; ++i)
    wsplit<<<(wl[i].n + 255) / 256, 256, 0, stream>>>(W(wl[i].src), Wb + wl[i].off,
                                                      wl[i].n);
  hipMemsetAsync(h0s, 0, (size_t)2 * ASZ * sizeof(short), stream);
  hipMemsetAsync(bar, 0, 2 * sizeof(int), stream);

  hipFuncSetAttribute((const void*)eltm_persist,
                      hipFuncAttributeMaxDynamicSharedMemorySize, 147456);
  PArgs pa;
  pa.x = x;
  pa.Wb = Wb;
  pa.h0s = h0s;
  pa.h1s = h1s;
  pa.xn0 = xn0;
  pa.hn0 = hn0;
  pa.ch0 = ch0;
  pa.xn1 = xn1;
  pa.hn1 = hn1;
  pa.ch1 = ch1;
  pa.o0 = o0;
  pa.o1 = o1;
  pa.bhi0 = W(3);
  pa.bcho0 = W(9);
  pa.bhi1 = W(14);
  pa.bcho1 = W(20);
  pa.out = out;
  pa.cnt = bar;
  pa.gen = bar + 1;
  eltm_persist<<<NB_, 512, 147456, stream>>>(pa);

  eltm_kLN<<<16384, 256, 0, stream>>>(out, W(23), W(24));
#undef W
}

// Round 4
// 80235.339 us; speedup vs baseline: 3.7358x; 3.7358x over previous
//
#include <hip/hip_runtime.h>
#include <hip/hip_bf16.h>

#define S_ 512
#define B_ 128
#define D_ 128
#define H_ 512
#define NB_ 240
#define NGRP 8
#define GSZ 30

typedef short bf16x8 __attribute__((ext_vector_type(8)));
typedef int i32x4 __attribute__((ext_vector_type(4)));
typedef float f32x4 __attribute__((ext_vector_type(4)));

// ---- weight plane offsets (in shorts). 3 planes, plane stride WPLANE. ----
#define OFF0_XI   0
#define OFF0_HI   131072
#define OFF0_OX   655360
#define OFF0_OH   720896
#define OFF0_IO   983040
#define OFF0_HO   1245184
#define OFF0_CHO  1507328
#define OFF0_A    1769472
#define OFF0_B    2031616
#define OFF1_XI   2293760
#define OFF1_HI   2818048
#define OFF1_OX   3342336
#define OFF1_OH   3604480
#define OFF1_IO   3866624
#define OFF1_HO   4128768
#define OFF1_CHO  4390912
#define OFF1_A    4653056
#define OFF1_B    4915200
#define WPLANE    5177344
#define APLANE    65536

__device__ __forceinline__ float sigf(float x) { return 1.0f / (1.0f + expf(-x)); }

__device__ __forceinline__ short bfs(float v) {
  __hip_bfloat16 h = __float2bfloat16(v);
  return __builtin_bit_cast(short, h);
}
__device__ __forceinline__ float bff(short s) {
  __hip_bfloat16 h = __builtin_bit_cast(__hip_bfloat16, s);
  return __bfloat162float(h);
}
__device__ __forceinline__ float u2f(unsigned int u) {
  return __uint_as_float(u << 16);
}

// ---- sc1 (agent-coherent, L2-bypass) memory ops ----
__device__ __forceinline__ i32x4 ldg16_sc(const short* p) {
  i32x4 o;
  asm volatile("global_load_dwordx4 %0, %1, off sc1" : "=v"(o) : "v"(p));
  return o;
}
__device__ __forceinline__ i32x4 ldg16_pl(const short* p) {  // plain cached
  i32x4 o;
  asm volatile("global_load_dwordx4 %0, %1, off" : "=v"(o) : "v"(p));
  return o;
}
__device__ __forceinline__ unsigned int ldgu16_sc(const short* p) {
  unsigned int o;
  asm volatile("global_load_ushort %0, %1, off sc1" : "=v"(o) : "v"(p));
  return o;
}
__device__ __forceinline__ void stg16_sc(short* p, unsigned int v) {
  asm volatile("global_store_short %0, %1, off sc1" ::"v"(p), "v"(v) : "memory");
}
#define VMDRAIN()                                       \
  do {                                                  \
    asm volatile("s_waitcnt vmcnt(0)" ::: "memory");    \
    __builtin_amdgcn_sched_barrier(0);                  \
  } while (0)

// split-store one fp32 as 3 bf16 planes, sc1-coherent
__device__ __forceinline__ void st3g(short* buf, int idx, float v) {
  short s0 = bfs(v);
  float f0 = bff(s0);
  float r1 = v - f0;
  short s1 = bfs(r1);
  float f1 = bff(s1);
  short s2 = bfs(r1 - f1);
  stg16_sc(buf + idx, (unsigned int)(unsigned short)s0);
  stg16_sc(buf + idx + APLANE, (unsigned int)(unsigned short)s1);
  stg16_sc(buf + idx + 2 * APLANE, (unsigned int)(unsigned short)s2);
}

#define MFMA16(a, b, c) __builtin_amdgcn_mfma_f32_16x16x32_bf16(a, b, c, 0, 0, 0)

__device__ __forceinline__ void mac6(f32x4& acc, const bf16x8& a0, const bf16x8& a1,
                                     const bf16x8& a2, const bf16x8& W0,
                                     const bf16x8& W1, const bf16x8& W2) {
  acc = MFMA16(a0, W0, acc);
  acc = MFMA16(a0, W1, acc);
  acc = MFMA16(a1, W0, acc);
  acc = MFMA16(a0, W2, acc);
  acc = MFMA16(a1, W1, acc);
  acc = MFMA16(a2, W0, acc);
}

struct AFrag {
  bf16x8 a0, a1, a2;
};

// on-the-fly 3-plane split of fp32 input x (plain cached loads)
__device__ __forceinline__ AFrag ldAx(const float* base) {
  AFrag f;
#pragma unroll
  for (int e = 0; e < 8; ++e) {
    float xv = base[e];
    short s0 = bfs(xv);
    float f0 = bff(s0);
    float r1 = xv - f0;
    short s1 = bfs(r1);
    float f1 = bff(s1);
    short s2 = bfs(r1 - f1);
    f.a0[e] = s0;
    f.a1[e] = s1;
    f.a2[e] = s2;
  }
  return f;
}
__device__ __forceinline__ void mac6A(f32x4& acc, const AFrag& A, const bf16x8& W0,
                                      const bf16x8& W1, const bf16x8& W2) {
  mac6(acc, A.a0, A.a1, A.a2, W0, W1, W2);
}

// LDS weight slab read, XOR-swizzled
__device__ __forceinline__ bf16x8 ldW(int slab, int K2, int r, int kb) {
  extern __shared__ char smem[];
  return *(const bf16x8*)(smem + slab + ((r * K2 + kb) ^ ((r & 7) << 4)));
}

// stage one 16-row x K plane slab global->LDS with the same swizzle (once)
__device__ __forceinline__ void stage(int slabBase, const short* src, int K) {
  extern __shared__ char smem[];
  const int kc8 = K / 8;
  const int chunks = 16 * kc8;
  for (int c = threadIdx.x; c < chunks; c += blockDim.x) {
    const int row = c / kc8, kc = c % kc8;
    bf16x8 v = *(const bf16x8*)(src + row * K + kc * 8);
    *(bf16x8*)(smem + slabBase + ((row * (2 * K) + kc * 16) ^ ((row & 7) << 4))) = v;
  }
}

#define BC(x) __builtin_bit_cast(bf16x8, x)

// ---- pipelined GEMV slab units (K=512, 16 ks). A: 3-plane sc1 global. ----
__device__ __forceinline__ void unit_h1(f32x4& acc, const short* aRow, int s0, int s1,
                                        int s2, int r, int g) {
#pragma unroll
  for (int b = 0; b < 2; ++b) {
    i32x4 A0[8], A1[8], A2[8];
    const short* pp = aRow + b * 256;
#pragma unroll
    for (int ks = 0; ks < 8; ++ks) {
      A0[ks] = ldg16_sc(pp + ks * 32);
      A1[ks] = ldg16_sc(pp + ks * 32 + APLANE);
      A2[ks] = ldg16_sc(pp + ks * 32 + 2 * APLANE);
    }
    VMDRAIN();
#pragma unroll
    for (int ks = 0; ks < 8; ++ks) {
      const int kb = (b * 8 + ks) * 64 + g * 16;
      mac6(acc, BC(A0[ks]), BC(A1[ks]), BC(A2[ks]), ldW(s0, 1024, r, kb),
           ldW(s1, 1024, r, kb), ldW(s2, 1024, r, kb));
    }
  }
}

__device__ __forceinline__ void unit_h2_lds(f32x4& acc0, f32x4& acc1, const short* aRow,
                                            int sa0, int sa1, int sa2, int sb0, int sb1,
                                            int sb2, int r, int g) {
#pragma unroll
  for (int b = 0; b < 2; ++b) {
    i32x4 A0[8], A1[8], A2[8];
    const short* pp = aRow + b * 256;
#pragma unroll
    for (int ks = 0; ks < 8; ++ks) {
      A0[ks] = ldg16_sc(pp + ks * 32);
      A1[ks] = ldg16_sc(pp + ks * 32 + APLANE);
      A2[ks] = ldg16_sc(pp + ks * 32 + 2 * APLANE);
    }
    VMDRAIN();
#pragma unroll
    for (int ks = 0; ks < 8; ++ks) {
      const int kb = (b * 8 + ks) * 64 + g * 16;
      mac6(acc0, BC(A0[ks]), BC(A1[ks]), BC(A2[ks]), ldW(sa0, 1024, r, kb),
           ldW(sa1, 1024, r, kb), ldW(sa2, 1024, r, kb));
      mac6(acc1, BC(A0[ks]), BC(A1[ks]), BC(A2[ks]), ldW(sb0, 1024, r, kb),
           ldW(sb1, 1024, r, kb), ldW(sb2, 1024, r, kb));
    }
  }
}

// gate unit with plane-2 weights streamed from global (plain/cached)
__device__ __forceinline__ void unit_h2_gw2(f32x4& acc0, f32x4& acc1, const short* aRow,
                                            int sa0, int sa1, const short* w2a, int sb0,
                                            int sb1, const short* w2b, int r, int g) {
#pragma unroll
  for (int b = 0; b < 4; ++b) {
    i32x4 A0[4], A1[4], A2[4], Wa[4], Wb2[4];
    const short* pp = aRow + b * 128;
#pragma unroll
    for (int ks = 0; ks < 4; ++ks) {
      A0[ks] = ldg16_sc(pp + ks * 32);
      A1[ks] = ldg16_sc(pp + ks * 32 + APLANE);
      A2[ks] = ldg16_sc(pp + ks * 32 + 2 * APLANE);
      Wa[ks] = ldg16_pl(w2a + b * 128 + ks * 32);
      Wb2[ks] = ldg16_pl(w2b + b * 128 + ks * 32);
    }
    VMDRAIN();
#pragma unroll
    for (int ks = 0; ks < 4; ++ks) {
      const int kb = (b * 4 + ks) * 64 + g * 16;
      mac6(acc0, BC(A0[ks]), BC(A1[ks]), BC(A2[ks]), ldW(sa0, 1024, r, kb),
           ldW(sa1, 1024, r, kb), BC(Wa[ks]));
      mac6(acc1, BC(A0[ks]), BC(A1[ks]), BC(A2[ks]), ldW(sb0, 1024, r, kb),
           ldW(sb1, 1024, r, kb), BC(Wb2[ks]));
    }
  }
}

// ---- fence-free grid barrier: monotonic grouped relaxed atomics ----
// bar layout (uints): [grp*32] group counters, [256] master, [288] gen
__device__ __forceinline__ void gbar(unsigned int* bar, unsigned int t, int grp) {
  asm volatile("s_waitcnt vmcnt(0) lgkmcnt(0)" ::: "memory");  // per-wave drain
  __syncthreads();
  if (threadIdx.x == 0) {
    unsigned int a = __hip_atomic_fetch_add(&bar[grp * 32], 1u, __ATOMIC_RELAXED,
                                            __HIP_MEMORY_SCOPE_AGENT);
    if (a == t * GSZ - 1) {
      unsigned int m = __hip_atomic_fetch_add(&bar[256], 1u, __ATOMIC_RELAXED,
                                              __HIP_MEMORY_SCOPE_AGENT);
      if (m == t * NGRP - 1)
        __hip_atomic_store(&bar[288], t, __ATOMIC_RELAXED, __HIP_MEMORY_SCOPE_AGENT);
    }
    while (__hip_atomic_load(&bar[288], __ATOMIC_RELAXED, __HIP_MEMORY_SCOPE_AGENT) < t)
      __builtin_amdgcn_s_sleep(1);
  }
  __syncthreads();
  __builtin_amdgcn_sched_barrier(0);
}

struct PArgs {
  const float* x;
  const short* Wb;
  short* h0s;
  short* h1s;
  short* xn0;
  short* hn0;
  short* ch0;
  short* xn1;
  short* hn1;
  short* ch1;
  short* o0;
  short* o1;
  const float* bhi0;
  const float* bcho0;
  const float* bhi1;
  const float* bcho1;
  float* out;
  unsigned int* bar;
};

// Block map: 0-31 L1-gate | 32-63 L0-gate | 64-79 L0 xn/hn | 80-111 L1 xn/hn
//            112-143 B-L0 | 144-175 B-L1 | 176-207 C-L0 | 208-239 C-L1
__global__ __launch_bounds__(512, 2) void eltm_persist(PArgs p) {
  const int bid = blockIdx.x;
  const int lane = threadIdx.x & 63;
  const int w = threadIdx.x >> 6;
  const int r = lane & 15;
  const int g = lane >> 4;
  const int grp = bid & 7;
  const f32x4 z = {0.f, 0.f, 0.f, 0.f};

  // ---------------- one-time LDS weight staging ----------------
  if (bid < 32) {
    const int j0 = bid * 16;
    stage(0, p.Wb + OFF1_XI + j0 * 512, 512);
    stage(16384, p.Wb + OFF1_XI + WPLANE + j0 * 512, 512);
    stage(32768, p.Wb + OFF1_HI + j0 * 512, 512);
    stage(49152, p.Wb + OFF1_HI + WPLANE + j0 * 512, 512);
    stage(65536, p.Wb + OFF1_XI + (512 + j0) * 512, 512);
    stage(81920, p.Wb + OFF1_XI + WPLANE + (512 + j0) * 512, 512);
    stage(98304, p.Wb + OFF1_HI + (512 + j0) * 512, 512);
    stage(114688, p.Wb + OFF1_HI + WPLANE + (512 + j0) * 512, 512);
  } else if (bid < 64) {
    const int j0 = (bid - 32) * 16;
    for (int pl = 0; pl < 3; ++pl) {
      stage(pl * 4096, p.Wb + OFF0_XI + pl * WPLANE + j0 * 128, 128);
      stage(12288 + pl * 4096, p.Wb + OFF0_XI + pl * WPLANE + (512 + j0) * 128, 128);
      stage(24576 + pl * 16384, p.Wb + OFF0_HI + pl * WPLANE + j0 * 512, 512);
      stage(73728 + pl * 16384, p.Wb + OFF0_HI + pl * WPLANE + (512 + j0) * 512, 512);
    }
  } else if (bid < 80) {
    const int j0 = (bid - 64) * 32;
    for (int c = 0; c < 2; ++c) {
      const int base = c * 61440;
      for (int pl = 0; pl < 3; ++pl) {
        stage(base + pl * 4096, p.Wb + OFF0_OX + pl * WPLANE + (j0 + c * 16) * 128, 128);
        stage(base + 12288 + pl * 16384,
              p.Wb + OFF0_OH + pl * WPLANE + (j0 + c * 16) * 512, 512);
      }
    }
  } else if (bid < 112) {
    const int j0 = (bid - 80) * 16;
    for (int pl = 0; pl < 3; ++pl) {
      stage(pl * 16384, p.Wb + OFF1_OX + pl * WPLANE + j0 * 512, 512);
      stage(49152 + pl * 16384, p.Wb + OFF1_OH + pl * WPLANE + j0 * 512, 512);
    }
  } else if (bid < 176) {
    const int L = bid >= 144;
    const int j0 = (bid - (L ? 144 : 112)) * 16;
    const int oio = L ? OFF1_IO : OFF0_IO;
    const int oho = L ? OFF1_HO : OFF0_HO;
    const int och = L ? OFF1_CHO : OFF0_CHO;
    for (int pl = 0; pl < 3; ++pl) {
      stage(pl * 16384, p.Wb + oio + pl * WPLANE + j0 * 512, 512);
      stage(49152 + pl * 16384, p.Wb + oho + pl * WPLANE + j0 * 512, 512);
      stage(98304 + pl * 16384, p.Wb + och + pl * WPLANE + j0 * 512, 512);
    }
  } else {
    const int L = bid >= 208;
    const int j0 = (bid - (L ? 208 : 176)) * 16;
    const int oa = L ? OFF1_A : OFF0_A;
    const int ob = L ? OFF1_B : OFF0_B;
    for (int pl = 0; pl < 3; ++pl) {
      stage(pl * 16384, p.Wb + oa + pl * WPLANE + j0 * 512, 512);
      stage(49152 + pl * 16384, p.Wb + ob + pl * WPLANE + j0 * 512, 512);
    }
  }
  __syncthreads();

  unsigned int bt = 0;

  // ---------------- recurrence ----------------
  for (int i = 0; i <= S_; ++i) {
    const int do0 = i < S_;
    const int do1 = i >= 1;
    const int m0 = w * 16;
    // ============ phase A ============
    if (bid < 32) {
      if (do1) {  // L1 gates -> ch1 (step i-1)
        const int j0 = bid * 16;
        const int n = j0 + r;
        const float bi = p.bhi1[n], bh = p.bhi1[512 + n];
        f32x4 ig = z, hg = z;
        unit_h2_gw2(ig, hg, p.h0s + (m0 + r) * H_ + g * 8, 0, 16384,
                    p.Wb + OFF1_XI + 2 * WPLANE + (j0 + r) * 512 + g * 8, 65536, 81920,
                    p.Wb + OFF1_XI + 2 * WPLANE + (512 + j0 + r) * 512 + g * 8, r, g);
        unit_h2_gw2(ig, hg, p.h1s + (m0 + r) * H_ + g * 8, 32768, 49152,
                    p.Wb + OFF1_HI + 2 * WPLANE + (j0 + r) * 512 + g * 8, 98304, 114688,
                    p.Wb + OFF1_HI + 2 * WPLANE + (512 + j0 + r) * 512 + g * 8, r, g);
#pragma unroll
        for (int e = 0; e < 4; ++e)
          st3g(p.ch1, (m0 + g * 4 + e) * H_ + n, sigf(ig[e] + bi) * tanhf(hg[e] + bh));
      }
    } else if (bid < 64) {
      if (do0) {  // L0 gates -> ch0 (step i)
        const int j0 = (bid - 32) * 16;
        const int n = j0 + r;
        const float bi = p.bhi0[n], bh = p.bhi0[512 + n];
        f32x4 ig = z, hg = z;
        const float* xr = p.x + (size_t)i * B_ * D_ + (m0 + r) * D_ + g * 8;
#pragma unroll
        for (int ks = 0; ks < 4; ++ks) {
          AFrag A = ldAx(xr + ks * 32);
          const int kb = ks * 64 + g * 16;
          mac6A(ig, A, ldW(0, 256, r, kb), ldW(4096, 256, r, kb), ldW(8192, 256, r, kb));
          mac6A(hg, A, ldW(12288, 256, r, kb), ldW(16384, 256, r, kb),
                ldW(20480, 256, r, kb));
        }
        unit_h2_lds(ig, hg, p.h0s + (m0 + r) * H_ + g * 8, 24576, 40960, 57344, 73728,
                    90112, 106496, r, g);
#pragma unroll
        for (int e = 0; e < 4; ++e)
          st3g(p.ch0, (m0 + g * 4 + e) * H_ + n, sigf(ig[e] + bi) * tanhf(hg[e] + bh));
      }
    } else if (bid < 80) {
      if (do0) {  // L0 xn,hn (step i)
        const int j0 = (bid - 64) * 32;
#pragma unroll
        for (int c = 0; c < 2; ++c) {
          const int base = c * 61440;
          const int n = j0 + c * 16 + r;
          f32x4 ax = z;
          const float* xr = p.x + (size_t)i * B_ * D_ + (m0 + r) * D_ + g * 8;
#pragma unroll
          for (int ks = 0; ks < 4; ++ks) {
            AFrag A = ldAx(xr + ks * 32);
            const int kb = ks * 64 + g * 16;
            mac6A(ax, A, ldW(base, 256, r, kb), ldW(base + 4096, 256, r, kb),
                  ldW(base + 8192, 256, r, kb));
          }
#pragma unroll
          for (int e = 0; e < 4; ++e)
            st3g(p.xn0, (m0 + g * 4 + e) * H_ + n, tanhf(ax[e]));
          f32x4 ah = z;
          unit_h1(ah, p.h0s + (m0 + r) * H_ + g * 8, base + 12288, base + 28672,
                  base + 45056, r, g);
#pragma unroll
          for (int e = 0; e < 4; ++e)
            st3g(p.hn0, (m0 + g * 4 + e) * H_ + n, tanhf(ah[e]));
        }
      }
    } else if (bid < 112) {
      if (do1) {  // L1 xn,hn (step i-1)
        const int j0 = (bid - 80) * 16;
        const int n = j0 + r;
        f32x4 ax = z;
        unit_h1(ax, p.h0s + (m0 + r) * H_ + g * 8, 0, 16384, 32768, r, g);
#pragma unroll
        for (int e = 0; e < 4; ++e)
          st3g(p.xn1, (m0 + g * 4 + e) * H_ + n, tanhf(ax[e]));
        f32x4 ah = z;
        unit_h1(ah, p.h1s + (m0 + r) * H_ + g * 8, 49152, 65536, 81920, r, g);
#pragma unroll
        for (int e = 0; e < 4; ++e)
          st3g(p.hn1, (m0 + g * 4 + e) * H_ + n, tanhf(ah[e]));
      }
    }
    ++bt;
    gbar(p.bar, bt, grp);

    // ============ phase B ============
    if (bid >= 112 && bid < 176) {
      const int L = bid >= 144;
      if (L ? do1 : do0) {
        const int j0 = (bid - (L ? 144 : 112)) * 16;
        const int n = j0 + r;
        const float bc = (L ? p.bcho1 : p.bcho0)[n];
        const short* xn = L ? p.xn1 : p.xn0;
        const short* hn = L ? p.hn1 : p.hn0;
        const short* ch = L ? p.ch1 : p.ch0;
        f32x4 acc = z;
        unit_h1(acc, xn + (m0 + r) * H_ + g * 8, 0, 16384, 32768, r, g);
        unit_h1(acc, hn + (m0 + r) * H_ + g * 8, 49152, 65536, 81920, r, g);
        unit_h1(acc, ch + (m0 + r) * H_ + g * 8, 98304, 114688, 131072, r, g);
        short* o = L ? p.o1 : p.o0;
#pragma unroll
        for (int e = 0; e < 4; ++e)
          st3g(o, (m0 + g * 4 + e) * H_ + n, sigf(acc[e] + bc));
      }
    }
    ++bt;
    gbar(p.bar, bt, grp);

    // ============ phase C ============
    if (bid >= 176) {
      const int L = bid >= 208;
      if (L ? do1 : do0) {
        const int j0 = (bid - (L ? 208 : 176)) * 16;
        const int n = j0 + r;
        const short* o = L ? p.o1 : p.o0;
        f32x4 aA = z, aB = z;
        unit_h2_lds(aA, aB, o + (m0 + r) * H_ + g * 8, 0, 16384, 32768, 49152, 65536,
                    81920, r, g);
        const short* xn = L ? p.xn1 : p.xn0;
        const short* hn = L ? p.hn1 : p.hn0;
        const short* ch = L ? p.ch1 : p.ch0;
        short* hs = L ? p.h1s : p.h0s;
        const int idx0 = (m0 + g * 4) * H_ + n;
        unsigned int dx[12], dh[12], dc[12];
#pragma unroll
        for (int e = 0; e < 4; ++e) {
          dx[e * 3] = ldgu16_sc(xn + idx0 + e * H_);
          dx[e * 3 + 1] = ldgu16_sc(xn + idx0 + e * H_ + APLANE);
          dx[e * 3 + 2] = ldgu16_sc(xn + idx0 + e * H_ + 2 * APLANE);
          dh[e * 3] = ldgu16_sc(hn + idx0 + e * H_);
          dh[e * 3 + 1] = ldgu16_sc(hn + idx0 + e * H_ + APLANE);
          dh[e * 3 + 2] = ldgu16_sc(hn + idx0 + e * H_ + 2 * APLANE);
          dc[e * 3] = ldgu16_sc(ch + idx0 + e * H_);
          dc[e * 3 + 1] = ldgu16_sc(ch + idx0 + e * H_ + APLANE);
          dc[e * 3 + 2] = ldgu16_sc(ch + idx0 + e * H_ + 2 * APLANE);
        }
        VMDRAIN();
#pragma unroll
        for (int e = 0; e < 4; ++e) {
          const float xv = u2f(dx[e * 3]) + u2f(dx[e * 3 + 1]) + u2f(dx[e * 3 + 2]);
          const float hv = u2f(dh[e * 3]) + u2f(dh[e * 3 + 1]) + u2f(dh[e * 3 + 2]);
          const float cv = u2f(dc[e * 3]) + u2f(dc[e * 3 + 1]) + u2f(dc[e * 3 + 2]);
          const float av = aA[e], bv = aB[e];
          const float hval = av * xv + bv * hv + (1.f - av - bv) * cv;
          st3g(hs, idx0 + e * H_, hval);
          if (L) p.out[(size_t)(i - 1) * B_ * H_ + idx0 + e * H_] = hval;
        }
      }
    }
    ++bt;
    gbar(p.bar, bt, grp);
  }
}

// ---------------- prologue: split fp32 weights into 3 bf16 planes ----------------
__global__ void wsplit(const float* __restrict__ src, short* __restrict__ dst, int n) {
  int i = blockIdx.x * 256 + threadIdx.x;
  if (i >= n) return;
  float v = src[i];
  short s0 = bfs(v);
  float f0 = bff(s0);
  float r1 = v - f0;
  short s1 = bfs(r1);
  float f1 = bff(s1);
  short s2 = bfs(r1 - f1);
  dst[i] = s0;
  dst[i + WPLANE] = s1;
  dst[i + 2 * WPLANE] = s2;
}

// ---------------- final: in-place sinrelu + LayerNorm over H on d_out ----------------
__global__ void eltm_kLN(float* __restrict__ out, const float* __restrict__ g,
                         const float* __restrict__ bta) {
  const int row = blockIdx.x * 4 + (threadIdx.x >> 6);
  const int lane = threadIdx.x & 63;
  float* r = out + (size_t)row * H_;
  float v[8];
  float s = 0.f, s2 = 0.f;
#pragma unroll
  for (int i = 0; i < 8; ++i) {
    float x = r[lane + i * 64];
    float sv = (x >= 0.f) ? (x + sinf(x)) : 0.f;
    v[i] = sv;
    s += sv;
    s2 += sv * sv;
  }
#pragma unroll
  for (int m = 1; m < 64; m <<= 1) {
    s += __shfl_xor(s, m);
    s2 += __shfl_xor(s2, m);
  }
  const float mean = s * (1.f / 512.f);
  const float var = s2 * (1.f / 512.f) - mean * mean;
  const float rstd = rsqrtf(var + 1e-5f);
#pragma unroll
  for (int i = 0; i < 8; ++i) {
    const int c = lane + i * 64;
    r[c] = (v[i] - mean) * rstd * g[c] + bta[c];
  }
}

extern "C" void kernel_launch(void* const* d_in, const int* in_sizes, int n_in,
                              void* d_out, int out_size, void* d_ws, size_t ws_size,
                              hipStream_t stream) {
  const float* x = (const float*)d_in[0];
#define W(i) ((const float*)d_in[i])
  short* Wb = (short*)d_ws;
  short* acts = (short*)((char*)d_ws + (size_t)3 * WPLANE * 2);
  const int ASZ = 3 * APLANE;
  short* h0s = acts;
  short* h1s = acts + ASZ;
  short* xn0 = acts + 2 * ASZ;
  short* hn0 = acts + 3 * ASZ;
  short* ch0 = acts + 4 * ASZ;
  short* xn1 = acts + 5 * ASZ;
  short* hn1 = acts + 6 * ASZ;
  short* ch1 = acts + 7 * ASZ;
  short* o0 = acts + 8 * ASZ;
  short* o1 = acts + 9 * ASZ;
  unsigned int* bar = (unsigned int*)(acts + 10 * ASZ);
  float* out = (float*)d_out;

  struct {
    int src;
    int off;
    int n;
  } wl[18] = {{1, OFF0_XI, 131072},   {2, OFF0_HI, 524288},  {4, OFF0_OX, 65536},
              {5, OFF0_OH, 262144},   {6, OFF0_IO, 262144},  {7, OFF0_HO, 262144},
              {8, OFF0_CHO, 262144},  {10, OFF0_A, 262144},  {11, OFF0_B, 262144},
              {12, OFF1_XI, 524288},  {13, OFF1_HI, 524288}, {15, OFF1_OX, 262144},
              {16, OFF1_OH, 262144},  {17, OFF1_IO, 262144}, {18, OFF1_HO, 262144},
              {19, OFF1_CHO, 262144}, {21, OFF1_A, 262144},  {22, OFF1_B, 262144}};
  for (int i = 0; i < 18; ++i)
    wsplit<<<(wl[i].n + 255) / 256, 256, 0, stream>>>(W(wl[i].src), Wb + wl[i].off,
                                                      wl[i].n);
  hipMemsetAsync(h0s, 0, (size_t)2 * ASZ * sizeof(short), stream);
  hipMemsetAsync(bar, 0, 4096, stream);

  hipFuncSetAttribute((const void*)eltm_persist,
                      hipFuncAttributeMaxDynamicSharedMemorySize, 147456);
  PArgs pa;
  pa.x = x;
  pa.Wb = Wb;
  pa.h0s = h0s;
  pa.h1s = h1s;
  pa.xn0 = xn0;
  pa.hn0 = hn0;
  pa.ch0 = ch0;
  pa.xn1 = xn1;
  pa.hn1 = hn1;
  pa.ch1 = ch1;
  pa.o0 = o0;
  pa.o1 = o1;
  pa.bhi0 = W(3);
  pa.bcho0 = W(9);
  pa.bhi1 = W(14);
  pa.bcho1 = W(20);
  pa.out = out;
  pa.bar = bar;
  eltm_persist<<<NB_, 512, 147456, stream>>>(pa);

  eltm_kLN<<<16384, 256, 0, stream>>>(out, W(23), W(24));
#undef W
}